// Round 1
// baseline (1403.755 us; speedup 1.0000x reference)
//
#include <hip/hip_runtime.h>
#include <stdint.h>

// Swin block: B=64, H=W=56, C=128, HID=512, WS=7, NH=4, SHIFT=3
static constexpr int Bz   = 64;
static constexpr int HH   = 56, WWp = 56;
static constexpr int C    = 128, HID = 512;
static constexpr int L    = HH * WWp;        // 3136
static constexpr int M    = Bz * L;          // 200704
static constexpr int NWIN = Bz * 64;         // 4096 windows
static constexpr int NH   = 4;
static constexpr int SHIFT = 3;

__device__ __forceinline__ float bf2f(unsigned short u) {
    return __uint_as_float(((unsigned int)u) << 16);
}
__device__ __forceinline__ unsigned short f2bf(float f) {
    unsigned int u = __float_as_uint(f);
    return (unsigned short)((u + 0x7FFFu + ((u >> 16) & 1u)) >> 16);
}

// window-order row m -> original (b,l) row. Same permutation works as gather
// (qkv input) and scatter (proj output): roll(-3) + 7x7 partition.
__global__ void rowmap_kernel(int* __restrict__ rowmap) {
    int m = blockIdx.x * 256 + threadIdx.x;
    int w = m / 49, t = m - w * 49;
    int b = w >> 6, wi = (w >> 3) & 7, wj = w & 7;
    int ti = t / 7, tj = t - ti * 7;
    int i = wi * 7 + ti, j = wj * 7 + tj;
    int io = i + SHIFT; if (io >= HH) io -= HH;
    int jo = j + SHIFT; if (jo >= WWp) jo -= WWp;
    rowmap[m] = b * L + io * WWp + jo;
}

// LayerNorm over C=128, fp32 in -> bf16 out. 1 wave per row, 4 rows/block.
__global__ __launch_bounds__(256) void ln_kernel(const float* __restrict__ in,
                                                 const float* __restrict__ g,
                                                 const float* __restrict__ bta,
                                                 unsigned short* __restrict__ out) {
    int row  = blockIdx.x * 4 + (threadIdx.x >> 6);
    int lane = threadIdx.x & 63;
    const float2 v = ((const float2*)(in + (long)row * C))[lane];
    float s  = v.x + v.y;
    float ss = v.x * v.x + v.y * v.y;
#pragma unroll
    for (int off = 32; off >= 1; off >>= 1) {
        s  += __shfl_xor(s, off);
        ss += __shfl_xor(ss, off);
    }
    float mu  = s * (1.0f / C);
    float var = ss * (1.0f / C) - mu * mu;
    float rs  = rsqrtf(var + 1e-5f);
    float2 gg = ((const float2*)g)[lane];
    float2 bb = ((const float2*)bta)[lane];
    ushort2 o;
    o.x = f2bf((v.x - mu) * rs * gg.x + bb.x);
    o.y = f2bf((v.y - mu) * rs * gg.y + bb.y);
    ((ushort2*)(out + (long)row * C))[lane] = o;
}

// Generic NT GEMM: out[m,n] = sum_k A[m,k] * W[n,k]  (A bf16, W fp32)
// 64x64 tile, 256 threads, 4x4 microtile. LDS tiles stored K-major so the
// inner loop is 2x ds_read_b128 + 16 FMA per k (conflict-free).
// MODE 0: qkv   (gather A rows via rowmap; scatter n into q/k/v (w,h,t,d) bf16)
// MODE 1: proj  (scatter rows via rowmap; += resid; fp32 out)
// MODE 2: fc1   (exact gelu; bf16 out)
// MODE 3: fc2   (+= resid; fp32 out = d_out)
template<int MODE, int K, bool GATHER>
__global__ __launch_bounds__(256) void gemm_bt(
    const unsigned short* __restrict__ A,
    const float* __restrict__ W,
    const float* __restrict__ bias,
    const int* __restrict__ rowmap,
    const float* __restrict__ resid,
    float* __restrict__ outf,
    unsigned short* __restrict__ o0,
    unsigned short* __restrict__ o1,
    unsigned short* __restrict__ o2)
{
    __shared__ float As[32][64];
    __shared__ float Wt[32][64];
    const int tid = threadIdx.x;
    const int tx = tid & 15, ty = tid >> 4;
    const int mbase = blockIdx.x * 64;
    const int nbase = blockIdx.y * 64;
    float acc[4][4] = {};

    for (int kb = 0; kb < K; kb += 32) {
#pragma unroll
        for (int vv = 0; vv < 2; ++vv) {
            int v = tid + vv * 256;
            int r = v >> 3, kc = (v & 7) << 2;
            long arow = GATHER ? (long)rowmap[mbase + r] : (long)(mbase + r);
            const ushort4 a4 = *(const ushort4*)(A + arow * K + kb + kc);
            As[kc + 0][r] = bf2f(a4.x);
            As[kc + 1][r] = bf2f(a4.y);
            As[kc + 2][r] = bf2f(a4.z);
            As[kc + 3][r] = bf2f(a4.w);
            const float4 w4 = *(const float4*)(W + (long)(nbase + r) * K + kb + kc);
            Wt[kc + 0][r] = w4.x;
            Wt[kc + 1][r] = w4.y;
            Wt[kc + 2][r] = w4.z;
            Wt[kc + 3][r] = w4.w;
        }
        __syncthreads();
#pragma unroll
        for (int kk = 0; kk < 32; ++kk) {
            const float4 a4 = *(const float4*)&As[kk][ty << 2];
            const float4 b4 = *(const float4*)&Wt[kk][tx << 2];
            float a[4] = {a4.x, a4.y, a4.z, a4.w};
            float b[4] = {b4.x, b4.y, b4.z, b4.w};
#pragma unroll
            for (int i2 = 0; i2 < 4; ++i2)
#pragma unroll
                for (int j2 = 0; j2 < 4; ++j2)
                    acc[i2][j2] = fmaf(a[i2], b[j2], acc[i2][j2]);
        }
        __syncthreads();
    }

#pragma unroll
    for (int i2 = 0; i2 < 4; ++i2) {
        const int gm = mbase + (ty << 2) + i2;
#pragma unroll
        for (int j2 = 0; j2 < 4; ++j2) {
            const int gn = nbase + (tx << 2) + j2;
            float val = acc[i2][j2] + bias[gn];
            if constexpr (MODE == 0) {
                int part = gn >> 7, rem = gn & 127;
                int hh = rem >> 5, dd = rem & 31;
                int w = gm / 49, t = gm - w * 49;
                long dst = (((long)(w * NH + hh) * 49) + t) * 32 + dd;
                unsigned short bv = f2bf(val);
                if (part == 0)      o0[dst] = bv;
                else if (part == 1) o1[dst] = bv;
                else                o2[dst] = bv;
            } else if constexpr (MODE == 1) {
                long r = rowmap[gm];
                outf[r * C + gn] = resid[r * C + gn] + val;
            } else if constexpr (MODE == 2) {
                float ge = 0.5f * val * (1.0f + erff(val * 0.70710678118654752f));
                o0[(long)gm * HID + gn] = f2bf(ge);
            } else {
                outf[(long)gm * C + gn] = resid[(long)gm * C + gn] + val;
            }
        }
    }
}

// Attention: 1 block per window, 1 wave per head, lane i (<49) owns row i.
// K,V staged in LDS (fp32); scores/softmax fully in registers.
__global__ __launch_bounds__(256) void attn_kernel(
    const unsigned short* __restrict__ qb,
    const unsigned short* __restrict__ kb,
    const unsigned short* __restrict__ vb,
    const float* __restrict__ rpb,
    unsigned short* __restrict__ ob)
{
    __shared__ float Ks[NH][49][32];
    __shared__ float Vs[NH][49][32];
    const int w = blockIdx.x;
    const int tid = threadIdx.x;
    const long base = (long)w * (NH * 49 * 32);
    float* ksf = &Ks[0][0][0];
    float* vsf = &Vs[0][0][0];
    for (int idx = tid; idx < NH * 49 * 32; idx += 256) {
        ksf[idx] = bf2f(kb[base + idx]);
        vsf[idx] = bf2f(vb[base + idx]);
    }
    __syncthreads();
    const int h = tid >> 6;
    const int lane = tid & 63;
    if (lane >= 49) return;
    const int i = lane;
    const int yi = i / 7, xi = i - yi * 7;
    float q[32];
    const unsigned short* qp = qb + base + ((h * 49 + i) * 32);
#pragma unroll
    for (int d = 0; d < 32; ++d) q[d] = bf2f(qp[d]);
    const float scale = 0.17677669529663687f;  // 1/sqrt(32)
    float s[49];
#pragma unroll
    for (int j = 0; j < 49; ++j) {
        const float* kr = &Ks[h][j][0];
        float dot = 0.f;
#pragma unroll
        for (int d = 0; d < 32; ++d) dot = fmaf(q[d], kr[d], dot);
        int yj = j / 7, xj = j - yj * 7;
        int ridx = (yi - yj + 6) * 13 + (xi - xj + 6);
        s[j] = dot * scale + rpb[ridx * NH + h];
    }
    float mx = -1e30f;
#pragma unroll
    for (int j = 0; j < 49; ++j) mx = fmaxf(mx, s[j]);
    float sum = 0.f;
#pragma unroll
    for (int j = 0; j < 49; ++j) { s[j] = __expf(s[j] - mx); sum += s[j]; }
    float inv = 1.0f / sum;
    float o[32] = {};
#pragma unroll
    for (int j = 0; j < 49; ++j) {
        float p = s[j];
        const float* vr = &Vs[h][j][0];
#pragma unroll
        for (int d = 0; d < 32; ++d) o[d] = fmaf(p, vr[d], o[d]);
    }
    unsigned short* op = ob + ((long)(w * 49 + i)) * C + h * 32;
#pragma unroll
    for (int d = 0; d < 32; ++d) op[d] = f2bf(o[d] * inv);
}

extern "C" void kernel_launch(void* const* d_in, const int* in_sizes, int n_in,
                              void* d_out, int out_size, void* d_ws, size_t ws_size,
                              hipStream_t stream) {
    const float* x      = (const float*)d_in[0];
    const float* n1g    = (const float*)d_in[1];
    const float* n1b    = (const float*)d_in[2];
    const float* qkv_w  = (const float*)d_in[3];
    const float* qkv_b  = (const float*)d_in[4];
    const float* proj_w = (const float*)d_in[5];
    const float* proj_b = (const float*)d_in[6];
    const float* rpb    = (const float*)d_in[7];
    const float* n2g    = (const float*)d_in[8];
    const float* n2b    = (const float*)d_in[9];
    const float* fc1_w  = (const float*)d_in[10];
    const float* fc1_b  = (const float*)d_in[11];
    const float* fc2_w  = (const float*)d_in[12];
    const float* fc2_b  = (const float*)d_in[13];
    float* out = (float*)d_out;

    // Workspace layout (~360.5 MB):
    //   [0 .. 4*SZ)      : hnorm | q | k | v   (bf16)  -> reused as h2 (M x 512 bf16)
    //   [4*SZ .. 5*SZ)   : o (bf16)            -> reused as h2norm
    //   [5*SZ .. +M*C*4) : x2 (fp32)
    //   then             : rowmap (int)
    char* ws = (char*)d_ws;
    const size_t SZ = (size_t)M * C * 2;  // 51,380,224 B
    unsigned short* hnorm = (unsigned short*)(ws);
    unsigned short* qq    = (unsigned short*)(ws + SZ);
    unsigned short* kk_   = (unsigned short*)(ws + 2 * SZ);
    unsigned short* vv_   = (unsigned short*)(ws + 3 * SZ);
    unsigned short* h2    = (unsigned short*)(ws);           // M x HID bf16 (reuse)
    unsigned short* ob    = (unsigned short*)(ws + 4 * SZ);  // o, later h2norm
    unsigned short* h2n   = ob;
    float* x2   = (float*)(ws + 5 * SZ);
    int* rowmap = (int*)(ws + 5 * SZ + (size_t)M * C * 4);

    rowmap_kernel<<<M / 256, 256, 0, stream>>>(rowmap);
    ln_kernel<<<M / 4, 256, 0, stream>>>(x, n1g, n1b, hnorm);
    gemm_bt<0, 128, true ><<<dim3(M / 64, 6), 256, 0, stream>>>(hnorm, qkv_w, qkv_b, rowmap, nullptr, nullptr, qq, kk_, vv_);
    attn_kernel<<<NWIN, 256, 0, stream>>>(qq, kk_, vv_, rpb, ob);
    gemm_bt<1, 128, false><<<dim3(M / 64, 2), 256, 0, stream>>>(ob, proj_w, proj_b, rowmap, x, x2, nullptr, nullptr, nullptr);
    ln_kernel<<<M / 4, 256, 0, stream>>>(x2, n2g, n2b, h2n);
    gemm_bt<2, 128, false><<<dim3(M / 64, 8), 256, 0, stream>>>(h2n, fc1_w, fc1_b, nullptr, nullptr, nullptr, h2, nullptr, nullptr);
    gemm_bt<3, 512, false><<<dim3(M / 64, 2), 256, 0, stream>>>(h2, fc2_w, fc2_b, nullptr, x2, out, nullptr, nullptr, nullptr);
}

// Round 2
// 619.191 us; speedup vs baseline: 2.2671x; 2.2671x over previous
//
#include <hip/hip_runtime.h>
#include <stdint.h>

// Swin block: B=64, H=W=56, C=128, HID=512, WS=7, NH=4, SHIFT=3
static constexpr int Bz   = 64;
static constexpr int HH   = 56, WWp = 56;
static constexpr int C    = 128, HID = 512;
static constexpr int L    = HH * WWp;        // 3136
static constexpr int M    = Bz * L;          // 200704
static constexpr int NWIN = Bz * 64;         // 4096 windows
static constexpr int NH   = 4;
static constexpr int SHIFT = 3;

typedef __bf16 bf16x8 __attribute__((ext_vector_type(8)));
typedef float  f32x4  __attribute__((ext_vector_type(4)));

__device__ __forceinline__ float bf2f(unsigned short u) {
    return __uint_as_float(((unsigned int)u) << 16);
}
__device__ __forceinline__ unsigned short f2bf(float f) {
    unsigned int u = __float_as_uint(f);
    return (unsigned short)((u + 0x7FFFu + ((u >> 16) & 1u)) >> 16);
}

// window-order row m -> original (b,l) row: roll(-SHIFT) + 7x7 partition.
__device__ __forceinline__ int win2orig(int m) {
    int w = m / 49, t = m - w * 49;
    int b = w >> 6, wi = (w >> 3) & 7, wj = w & 7;
    int ti = t / 7, tj = t - ti * 7;
    int i = wi * 7 + ti + SHIFT; if (i >= HH) i -= HH;
    int j = wj * 7 + tj + SHIFT; if (j >= WWp) j -= WWp;
    return b * L + i * WWp + j;
}

__device__ __forceinline__ void async_copy16(void* ldsdst, const void* gsrc) {
    __builtin_amdgcn_global_load_lds(
        (const __attribute__((address_space(1))) unsigned int*)gsrc,
        (__attribute__((address_space(3))) unsigned int*)ldsdst,
        16, 0, 0);
}

// Convert all weight matrices fp32 -> bf16 into one flat buffer.
// [0,49152): qkv_w  [49152,65536): proj_w  [65536,131072): fc1_w  [131072,196608): fc2_w
__global__ __launch_bounds__(256) void wconv_kernel(
    const float* __restrict__ qkvw, const float* __restrict__ projw,
    const float* __restrict__ fc1w, const float* __restrict__ fc2w,
    unsigned short* __restrict__ wb) {
    int i = blockIdx.x * 256 + threadIdx.x;
    float v;
    if (i < 49152)       v = qkvw[i];
    else if (i < 65536)  v = projw[i - 49152];
    else if (i < 131072) v = fc1w[i - 65536];
    else                 v = fc2w[i - 131072];
    wb[i] = f2bf(v);
}

// LayerNorm over C=128, fp32 or bf16 in -> bf16 out. 1 wave/row, 4 rows/block.
template<bool BF16IN>
__global__ __launch_bounds__(256) void ln_kernel(const void* __restrict__ in,
                                                 const float* __restrict__ g,
                                                 const float* __restrict__ bta,
                                                 unsigned short* __restrict__ out) {
    int row  = blockIdx.x * 4 + (threadIdx.x >> 6);
    int lane = threadIdx.x & 63;
    float2 v;
    if constexpr (BF16IN) {
        ushort2 u = ((const ushort2*)((const unsigned short*)in + (long)row * C))[lane];
        v.x = bf2f(u.x); v.y = bf2f(u.y);
    } else {
        v = ((const float2*)((const float*)in + (long)row * C))[lane];
    }
    float s  = v.x + v.y;
    float ss = v.x * v.x + v.y * v.y;
#pragma unroll
    for (int off = 32; off >= 1; off >>= 1) {
        s  += __shfl_xor(s, off);
        ss += __shfl_xor(ss, off);
    }
    float mu  = s * (1.0f / C);
    float var = ss * (1.0f / C) - mu * mu;
    float rs  = rsqrtf(var + 1e-5f);
    float2 gg = ((const float2*)g)[lane];
    float2 bb = ((const float2*)bta)[lane];
    ushort2 o;
    o.x = f2bf((v.x - mu) * rs * gg.x + bb.x);
    o.y = f2bf((v.y - mu) * rs * gg.y + bb.y);
    ((ushort2*)(out + (long)row * C))[lane] = o;
}

// MFMA NT GEMM: out[m,n] = sum_k A[m,k]*W[n,k], A,W bf16.
// 128x128 tile, 4 waves (2x2), each wave 64x64 via 4x4 frags of 16x16x32.
// LDS: A[128][128]+B[128][128] bf16 = 64KB, staged by global_load_lds(16B)
// with slot^(row&7) source pre-swizzle; ds_read_b128 frag reads use same XOR.
// MODE 0: qkv  (gather rows via win2orig; scatter to q/k/v (w,h,t,d) bf16)
// MODE 1: proj (scatter rows via win2orig; + resid fp32 x; bf16 out x2)
// MODE 2: fc1  (exact gelu; bf16 out)
// MODE 3: fc2  (+ resid bf16 x2; fp32 out = d_out)
template<int MODE, int K, bool GATHER>
__global__ __launch_bounds__(256) void gemm_mfma(
    const unsigned short* __restrict__ A,
    const unsigned short* __restrict__ Wb,
    const float* __restrict__ bias,
    const float* __restrict__ residf,
    const unsigned short* __restrict__ residb,
    float* __restrict__ outf,
    unsigned short* __restrict__ outb)
{
    __shared__ char lds[65536];
    char* Asm = lds;
    char* Bsm = lds + 32768;
    const int tid  = threadIdx.x;
    const int wid  = tid >> 6, lane = tid & 63;
    const int g    = lane >> 4, lr = lane & 15;
    const int wm   = wid >> 1,  wn = wid & 1;
    const int mbase = blockIdx.x * 128, nbase = blockIdx.y * 128;
    f32x4 acc[4][4] = {};

    for (int kb = 0; kb < K; kb += 128) {
        if (kb) __syncthreads();
#pragma unroll
        for (int is = 0; is < 8; ++is) {
            const int cb   = (is * 4 + wid) * 1024;      // dest byte offset in tile
            const int row  = (cb >> 8) + g;              // dest row (0..127)
            const int slot = lr ^ (row & 7);             // source 16B-slot pre-swizzle
            long arow = GATHER ? (long)win2orig(mbase + row) : (long)(mbase + row);
            async_copy16(Asm + cb, (const char*)A + (arow * K + kb) * 2 + slot * 16);
            async_copy16(Bsm + cb, (const char*)Wb + ((long)(nbase + row) * K + kb) * 2 + slot * 16);
        }
        __syncthreads();
#pragma unroll
        for (int kk = 0; kk < 4; ++kk) {
            bf16x8 af[4], bfr[4];
#pragma unroll
            for (int mi = 0; mi < 4; ++mi) {
                int r = wm * 64 + mi * 16 + lr;
                int s = (kk * 4 + g) ^ (r & 7);
                af[mi] = *(const bf16x8*)(Asm + r * 256 + s * 16);
            }
#pragma unroll
            for (int ni = 0; ni < 4; ++ni) {
                int r = wn * 64 + ni * 16 + lr;
                int s = (kk * 4 + g) ^ (r & 7);
                bfr[ni] = *(const bf16x8*)(Bsm + r * 256 + s * 16);
            }
#pragma unroll
            for (int mi = 0; mi < 4; ++mi)
#pragma unroll
                for (int ni = 0; ni < 4; ++ni)
                    acc[mi][ni] = __builtin_amdgcn_mfma_f32_16x16x32_bf16(af[mi], bfr[ni], acc[mi][ni], 0, 0, 0);
        }
    }

    // Epilogue. C/D: col = lane&15, row = (lane>>4)*4 + reg  [m89-verified]
#pragma unroll
    for (int ni = 0; ni < 4; ++ni) {
        const int gn = nbase + wn * 64 + ni * 16 + lr;
        const float bi = bias[gn];
#pragma unroll
        for (int mi = 0; mi < 4; ++mi) {
#pragma unroll
            for (int rg = 0; rg < 4; ++rg) {
                const int gm = mbase + wm * 64 + mi * 16 + g * 4 + rg;
                float val = acc[mi][ni][rg] + bi;
                if constexpr (MODE == 0) {
                    int part = gn >> 7, rem = gn & 127;
                    int hh = rem >> 5, dd = rem & 31;
                    int w = gm / 49, t = gm - w * 49;
                    long dst = (long)part * ((long)M * 128) +
                               (((long)(w * NH + hh) * 49) + t) * 32 + dd;
                    outb[dst] = f2bf(val);
                } else if constexpr (MODE == 1) {
                    long r = win2orig(gm);
                    outb[r * C + gn] = f2bf(residf[r * C + gn] + val);
                } else if constexpr (MODE == 2) {
                    float ge = 0.5f * val * (1.0f + erff(val * 0.70710678118654752f));
                    outb[(long)gm * HID + gn] = f2bf(ge);
                } else {
                    outf[(long)gm * C + gn] = bf2f(residb[(long)gm * C + gn]) + val;
                }
            }
        }
    }
}

// Attention: 1 block per window, 1 wave per head, lane i (<49) owns row i.
__global__ __launch_bounds__(256) void attn_kernel(
    const unsigned short* __restrict__ qb,
    const unsigned short* __restrict__ kb,
    const unsigned short* __restrict__ vb,
    const float* __restrict__ rpb,
    unsigned short* __restrict__ ob)
{
    __shared__ float Ks[NH][49][32];
    __shared__ float Vs[NH][49][32];
    const int w = blockIdx.x;
    const int tid = threadIdx.x;
    const long base = (long)w * (NH * 49 * 32);
    float* ksf = &Ks[0][0][0];
    float* vsf = &Vs[0][0][0];
    for (int idx = tid; idx < NH * 49 * 32; idx += 256) {
        ksf[idx] = bf2f(kb[base + idx]);
        vsf[idx] = bf2f(vb[base + idx]);
    }
    __syncthreads();
    const int h = tid >> 6;
    const int lane = tid & 63;
    if (lane >= 49) return;
    const int i = lane;
    const int yi = i / 7, xi = i - yi * 7;
    float q[32];
    const unsigned short* qp = qb + base + ((h * 49 + i) * 32);
#pragma unroll
    for (int d = 0; d < 32; ++d) q[d] = bf2f(qp[d]);
    const float scale = 0.17677669529663687f;  // 1/sqrt(32)
    float s[49];
#pragma unroll
    for (int j = 0; j < 49; ++j) {
        const float* kr = &Ks[h][j][0];
        float dot = 0.f;
#pragma unroll
        for (int d = 0; d < 32; ++d) dot = fmaf(q[d], kr[d], dot);
        int yj = j / 7, xj = j - yj * 7;
        int ridx = (yi - yj + 6) * 13 + (xi - xj + 6);
        s[j] = dot * scale + rpb[ridx * NH + h];
    }
    float mx = -1e30f;
#pragma unroll
    for (int j = 0; j < 49; ++j) mx = fmaxf(mx, s[j]);
    float sum = 0.f;
#pragma unroll
    for (int j = 0; j < 49; ++j) { s[j] = __expf(s[j] - mx); sum += s[j]; }
    float inv = 1.0f / sum;
    float o[32] = {};
#pragma unroll
    for (int j = 0; j < 49; ++j) {
        float p = s[j];
        const float* vr = &Vs[h][j][0];
#pragma unroll
        for (int d = 0; d < 32; ++d) o[d] = fmaf(p, vr[d], o[d]);
    }
    unsigned short* op = ob + ((long)(w * 49 + i)) * C + h * 32;
#pragma unroll
    for (int d = 0; d < 32; ++d) op[d] = f2bf(o[d] * inv);
}

extern "C" void kernel_launch(void* const* d_in, const int* in_sizes, int n_in,
                              void* d_out, int out_size, void* d_ws, size_t ws_size,
                              hipStream_t stream) {
    const float* x      = (const float*)d_in[0];
    const float* n1g    = (const float*)d_in[1];
    const float* n1b    = (const float*)d_in[2];
    const float* qkv_w  = (const float*)d_in[3];
    const float* qkv_b  = (const float*)d_in[4];
    const float* proj_w = (const float*)d_in[5];
    const float* proj_b = (const float*)d_in[6];
    const float* rpb    = (const float*)d_in[7];
    const float* n2g    = (const float*)d_in[8];
    const float* n2b    = (const float*)d_in[9];
    const float* fc1_w  = (const float*)d_in[10];
    const float* fc1_b  = (const float*)d_in[11];
    const float* fc2_w  = (const float*)d_in[12];
    const float* fc2_b  = (const float*)d_in[13];
    float* out = (float*)d_out;

    // Workspace (~309 MB):
    //  [0,SZ)     hnorm bf16            (reused as h2: M x 512 bf16 = [0,4SZ))
    //  [SZ,4SZ)   q,k,v bf16 (w,h,t,d)
    //  [4SZ,5SZ)  o bf16  (reused as h2norm)
    //  [5SZ,6SZ)  x2 bf16 (second residual, demoted to bf16)
    //  [6SZ,...)  weights bf16 (393KB)
    char* ws = (char*)d_ws;
    const size_t SZ = (size_t)M * C * 2;  // 51,380,224 B
    unsigned short* hnorm  = (unsigned short*)(ws);
    unsigned short* qkvbuf = (unsigned short*)(ws + SZ);
    unsigned short* qq     = qkvbuf;
    unsigned short* kk_    = (unsigned short*)(ws + 2 * SZ);
    unsigned short* vv_    = (unsigned short*)(ws + 3 * SZ);
    unsigned short* ob     = (unsigned short*)(ws + 4 * SZ);
    unsigned short* h2n    = ob;
    unsigned short* x2b    = (unsigned short*)(ws + 5 * SZ);
    unsigned short* h2     = (unsigned short*)(ws);
    unsigned short* wb     = (unsigned short*)(ws + 6 * SZ);
    unsigned short* wqkv = wb, *wproj = wb + 49152, *wfc1 = wb + 65536, *wfc2 = wb + 131072;

    wconv_kernel<<<768, 256, 0, stream>>>(qkv_w, proj_w, fc1_w, fc2_w, wb);
    ln_kernel<false><<<M / 4, 256, 0, stream>>>(x, n1g, n1b, hnorm);
    gemm_mfma<0, 128, true ><<<dim3(M / 128, 3), 256, 0, stream>>>(hnorm, wqkv, qkv_b, nullptr, nullptr, nullptr, qkvbuf);
    attn_kernel<<<NWIN, 256, 0, stream>>>(qq, kk_, vv_, rpb, ob);
    gemm_mfma<1, 128, false><<<dim3(M / 128, 1), 256, 0, stream>>>(ob, wproj, proj_b, x, nullptr, nullptr, x2b);
    ln_kernel<true ><<<M / 4, 256, 0, stream>>>(x2b, n2g, n2b, h2n);
    gemm_mfma<2, 128, false><<<dim3(M / 128, 4), 256, 0, stream>>>(h2n, wfc1, fc1_b, nullptr, nullptr, nullptr, h2);
    gemm_mfma<3, 512, false><<<dim3(M / 128, 1), 256, 0, stream>>>(h2, wfc2, fc2_b, nullptr, x2b, out, nullptr);
}

// Round 3
// 550.083 us; speedup vs baseline: 2.5519x; 1.1256x over previous
//
#include <hip/hip_runtime.h>
#include <stdint.h>

// Swin block: B=64, H=W=56, C=128, HID=512, WS=7, NH=4, SHIFT=3
static constexpr int Bz   = 64;
static constexpr int HH   = 56, WWp = 56;
static constexpr int C    = 128, HID = 512;
static constexpr int L    = HH * WWp;        // 3136
static constexpr int M    = Bz * L;          // 200704
static constexpr int NWIN = Bz * 64;         // 4096 windows
static constexpr int NH   = 4;
static constexpr int SHIFT = 3;

typedef __bf16 bf16x8 __attribute__((ext_vector_type(8)));
typedef float  f32x4  __attribute__((ext_vector_type(4)));

__device__ __forceinline__ float bf2f(unsigned short u) {
    return __uint_as_float(((unsigned int)u) << 16);
}
__device__ __forceinline__ unsigned short f2bf(float f) {
    unsigned int u = __float_as_uint(f);
    return (unsigned short)((u + 0x7FFFu + ((u >> 16) & 1u)) >> 16);
}
__device__ __forceinline__ unsigned lds_addr(const void* p) {
    return (unsigned)(size_t)(__attribute__((address_space(3))) const char*)p;
}

// window-order row m -> original (b,l) row: roll(-SHIFT) + 7x7 partition.
__device__ __forceinline__ int win2orig(int m) {
    int w = m / 49, t = m - w * 49;
    int b = w >> 6, wi = (w >> 3) & 7, wj = w & 7;
    int ti = t / 7, tj = t - ti * 7;
    int i = wi * 7 + ti + SHIFT; if (i >= HH) i -= HH;
    int j = wj * 7 + tj + SHIFT; if (j >= WWp) j -= WWp;
    return b * L + i * WWp + j;
}

__device__ __forceinline__ void async_copy16(void* ldsdst, const void* gsrc) {
    __builtin_amdgcn_global_load_lds(
        (const __attribute__((address_space(1))) unsigned int*)gsrc,
        (__attribute__((address_space(3))) unsigned int*)ldsdst,
        16, 0, 0);
}

// Weights fp32->bf16 (196608 elems) + bias fragment table (16384 floats).
// biasd layout: [h][lane][mi][ni][r], value = rpb bias for (i,j) of the
// QK^T D-fragment; -1e30 for j>=49, 0 for i>=49.
__global__ __launch_bounds__(256) void wconv_kernel(
    const float* __restrict__ qkvw, const float* __restrict__ projw,
    const float* __restrict__ fc1w, const float* __restrict__ fc2w,
    const float* __restrict__ rpb, float* __restrict__ biasd,
    unsigned short* __restrict__ wb) {
    int i = blockIdx.x * 256 + threadIdx.x;
    float v;
    if (i < 49152)       v = qkvw[i];
    else if (i < 65536)  v = projw[i - 49152];
    else if (i < 131072) v = fc1w[i - 65536];
    else                 v = fc2w[i - 131072];
    wb[i] = f2bf(v);
    if (i < 16384) {
        int h = i >> 12, l = (i >> 6) & 63, f = i & 63;
        int mi = f >> 4, ni = (f >> 2) & 3, r = f & 3;
        int ii = mi * 16 + (l >> 4) * 4 + r;
        int jj = ni * 16 + (l & 15);
        float bv;
        if (jj >= 49)      bv = -1e30f;
        else if (ii >= 49) bv = 0.f;
        else {
            int yi = ii / 7, xi = ii - yi * 7, yj = jj / 7, xj = jj - yj * 7;
            bv = rpb[((yi - yj + 6) * 13 + (xi - xj + 6)) * NH + h];
        }
        biasd[i] = bv;
    }
}

// LayerNorm over C=128, fp32 or bf16 in -> bf16 out. 1 wave/row, 4 rows/block.
template<bool BF16IN>
__global__ __launch_bounds__(256) void ln_kernel(const void* __restrict__ in,
                                                 const float* __restrict__ g,
                                                 const float* __restrict__ bta,
                                                 unsigned short* __restrict__ out) {
    int row  = blockIdx.x * 4 + (threadIdx.x >> 6);
    int lane = threadIdx.x & 63;
    float2 v;
    if constexpr (BF16IN) {
        ushort2 u = ((const ushort2*)((const unsigned short*)in + (long)row * C))[lane];
        v.x = bf2f(u.x); v.y = bf2f(u.y);
    } else {
        v = ((const float2*)((const float*)in + (long)row * C))[lane];
    }
    float s  = v.x + v.y;
    float ss = v.x * v.x + v.y * v.y;
#pragma unroll
    for (int off = 32; off >= 1; off >>= 1) {
        s  += __shfl_xor(s, off);
        ss += __shfl_xor(ss, off);
    }
    float mu  = s * (1.0f / C);
    float var = ss * (1.0f / C) - mu * mu;
    float rs  = rsqrtf(var + 1e-5f);
    float2 gg = ((const float2*)g)[lane];
    float2 bb = ((const float2*)bta)[lane];
    ushort2 o;
    o.x = f2bf((v.x - mu) * rs * gg.x + bb.x);
    o.y = f2bf((v.y - mu) * rs * gg.y + bb.y);
    ((ushort2*)(out + (long)row * C))[lane] = o;
}

// MFMA NT GEMM: out[m,n] = sum_k A[m,k]*W[n,k], A,W bf16. 128x128 tile,
// 4 waves (2x2), each wave 64x64 via 4x4 frags of 16x16x32.
// MODE 0: qkv (gather via win2orig; q scaled; k [wh][49][32]; v transposed [wh][32][64])
// MODE 1: proj (scatter via win2orig; + resid fp32 x; bf16 out x2)
// MODE 2: fc1 (exact gelu; bf16 out)
// MODE 3: fc2 (+ resid bf16 x2; fp32 out = d_out)
template<int MODE, int K, bool GATHER>
__global__ __launch_bounds__(256) void gemm_mfma(
    const unsigned short* __restrict__ A,
    const unsigned short* __restrict__ Wb,
    const float* __restrict__ bias,
    const float* __restrict__ residf,
    const unsigned short* __restrict__ residb,
    float* __restrict__ outf,
    unsigned short* __restrict__ outb)
{
    __shared__ char lds[65536];
    char* Asm = lds;
    char* Bsm = lds + 32768;
    const int tid  = threadIdx.x;
    const int wid  = tid >> 6, lane = tid & 63;
    const int g    = lane >> 4, lr = lane & 15;
    const int wm   = wid >> 1,  wn = wid & 1;
    const int mbase = blockIdx.x * 128, nbase = blockIdx.y * 128;
    f32x4 acc[4][4] = {};

    for (int kb = 0; kb < K; kb += 128) {
        if (kb) __syncthreads();
#pragma unroll
        for (int is = 0; is < 8; ++is) {
            const int cb   = (is * 4 + wid) * 1024;      // dest byte offset in tile
            const int row  = (cb >> 8) + g;              // dest row (0..127)
            const int slot = lr ^ (row & 7);             // source 16B-slot pre-swizzle
            long arow = GATHER ? (long)win2orig(mbase + row) : (long)(mbase + row);
            async_copy16(Asm + cb, (const char*)A + (arow * K + kb) * 2 + slot * 16);
            async_copy16(Bsm + cb, (const char*)Wb + ((long)(nbase + row) * K + kb) * 2 + slot * 16);
        }
        __syncthreads();
#pragma unroll
        for (int kk = 0; kk < 4; ++kk) {
            bf16x8 af[4], bfr[4];
#pragma unroll
            for (int mi = 0; mi < 4; ++mi) {
                int r = wm * 64 + mi * 16 + lr;
                int s = (kk * 4 + g) ^ (r & 7);
                af[mi] = *(const bf16x8*)(Asm + r * 256 + s * 16);
            }
#pragma unroll
            for (int ni = 0; ni < 4; ++ni) {
                int r = wn * 64 + ni * 16 + lr;
                int s = (kk * 4 + g) ^ (r & 7);
                bfr[ni] = *(const bf16x8*)(Bsm + r * 256 + s * 16);
            }
#pragma unroll
            for (int mi = 0; mi < 4; ++mi)
#pragma unroll
                for (int ni = 0; ni < 4; ++ni)
                    acc[mi][ni] = __builtin_amdgcn_mfma_f32_16x16x32_bf16(af[mi], bfr[ni], acc[mi][ni], 0, 0, 0);
        }
    }

    // Epilogue. C/D: col = lane&15, row = (lane>>4)*4 + reg
#pragma unroll
    for (int ni = 0; ni < 4; ++ni) {
        const int gn = nbase + wn * 64 + ni * 16 + lr;
        const float bi = bias[gn];
#pragma unroll
        for (int mi = 0; mi < 4; ++mi) {
#pragma unroll
            for (int rg = 0; rg < 4; ++rg) {
                const int gm = mbase + wm * 64 + mi * 16 + g * 4 + rg;
                float val = acc[mi][ni][rg] + bi;
                if constexpr (MODE == 0) {
                    int part = gn >> 7, rem = gn & 127;
                    int hh = rem >> 5, dd = rem & 31;
                    int w = gm / 49, t = gm - w * 49;
                    if (part == 2) {
                        outb[2L * M * 128 + (((long)(w * 4 + hh)) * 32 + dd) * 64 + t] = f2bf(val);
                    } else {
                        float vv = (part == 0) ? val * 0.17677669529663687f : val;
                        outb[(long)part * M * 128 + (((long)(w * 4 + hh)) * 49 + t) * 32 + dd] = f2bf(vv);
                    }
                } else if constexpr (MODE == 1) {
                    long r = win2orig(gm);
                    outb[r * C + gn] = f2bf(residf[r * C + gn] + val);
                } else if constexpr (MODE == 2) {
                    float ge = 0.5f * val * (1.0f + erff(val * 0.70710678118654752f));
                    outb[(long)gm * HID + gn] = f2bf(ge);
                } else {
                    outf[(long)gm * C + gn] = bf2f(residb[(long)gm * C + gn]) + val;
                }
            }
        }
    }
}

// MFMA attention: 1 block/window, 1 wave/head. Q,K direct-from-global frags,
// QK^T (16 mfma) -> register softmax (D-layout) -> P^T to LDS (4x16 subtiles,
// packed b64 writes) -> PV B-frags via ds_read_b64_tr_b16, V^T frags from
// global -> O^T (16 mfma) -> masked b64 stores.
__global__ __launch_bounds__(256) void attn_mfma(
    const unsigned short* __restrict__ qb,   // [wh][49][32], pre-scaled
    const unsigned short* __restrict__ kb,   // [wh][49][32]
    const unsigned short* __restrict__ vtb,  // [wh][32][64] (V^T, cols 49..63 junk)
    const float* __restrict__ biasd,         // [h][lane][mi][ni][r]
    unsigned short* __restrict__ ob)         // [w*49+t][128]
{
    __shared__ __align__(16) char Pt[4][8192];
    const int tid  = threadIdx.x;
    const int h    = tid >> 6;
    const int lane = tid & 63;
    const int g    = lane >> 4, lr = lane & 15;
    const int w    = blockIdx.x;
    const long wh  = (long)(w * 4 + h);
    const unsigned short* qp = qb  + wh * (49 * 32);
    const unsigned short* kp = kb  + wh * (49 * 32);
    const unsigned short* vp = vtb + wh * (32 * 64);

    bf16x8 qf[4], kf[4];
#pragma unroll
    for (int mi = 0; mi < 4; ++mi) {
        qf[mi] = *(const bf16x8*)(qp + (mi * 16 + lr) * 32 + g * 8);
        kf[mi] = *(const bf16x8*)(kp + (mi * 16 + lr) * 32 + g * 8);
    }
    f32x4 acc[4][4] = {};  // [mi][ni]: row i = mi*16+g*4+r, col j = ni*16+lr
#pragma unroll
    for (int mi = 0; mi < 4; ++mi)
#pragma unroll
        for (int ni = 0; ni < 4; ++ni)
            acc[mi][ni] = __builtin_amdgcn_mfma_f32_16x16x32_bf16(qf[mi], kf[ni], acc[mi][ni], 0, 0, 0);

    const float* bp = biasd + (h * 64 + lane) * 64;
    char* ptw = &Pt[h][0];
#pragma unroll
    for (int mi = 0; mi < 4; ++mi) {
#pragma unroll
        for (int ni = 0; ni < 4; ++ni)
            acc[mi][ni] += *(const f32x4*)(bp + mi * 16 + ni * 4);
        // force j>=49 (ni==3, lr>0) to -1e30 regardless of K-garbage (NaN-safe)
#pragma unroll
        for (int c = 0; c < 4; ++c)
            acc[mi][3][c] = (lr == 0) ? acc[mi][3][c] : -1e30f;
        f32x4 mx;
#pragma unroll
        for (int c = 0; c < 4; ++c)
            mx[c] = fmaxf(fmaxf(acc[mi][0][c], acc[mi][1][c]), fmaxf(acc[mi][2][c], acc[mi][3][c]));
#pragma unroll
        for (int off = 1; off <= 8; off <<= 1)
#pragma unroll
            for (int c = 0; c < 4; ++c)
                mx[c] = fmaxf(mx[c], __shfl_xor(mx[c], off));
        f32x4 sum = {};
#pragma unroll
        for (int ni = 0; ni < 4; ++ni)
#pragma unroll
            for (int c = 0; c < 4; ++c) {
                float e = __expf(acc[mi][ni][c] - mx[c]);
                acc[mi][ni][c] = e;
                sum[c] += e;
            }
#pragma unroll
        for (int off = 1; off <= 8; off <<= 1)
#pragma unroll
            for (int c = 0; c < 4; ++c)
                sum[c] += __shfl_xor(sum[c], off);
        f32x4 inv;
#pragma unroll
        for (int c = 0; c < 4; ++c)
            inv[c] = __builtin_amdgcn_rcpf(sum[c]);
        // write normalized P^T: tile (jb=j/4, ib=mi) at 4x16 subtile granularity
#pragma unroll
        for (int ni = 0; ni < 4; ++ni) {
            ushort4 pw;
            pw.x = f2bf(acc[mi][ni][0] * inv[0]);
            pw.y = f2bf(acc[mi][ni][1] * inv[1]);
            pw.z = f2bf(acc[mi][ni][2] * inv[2]);
            pw.w = f2bf(acc[mi][ni][3] * inv[3]);
            int jb  = ni * 4 + (lr >> 2);
            int tix = (((jb >> 3) * 2 + (jb & 1)) * 4 + mi) * 4 + ((jb >> 1) & 3);
            *(ushort4*)(ptw + tix * 128 + (lr & 3) * 32 + g * 8) = pw;
        }
    }
    __syncthreads();

    // V^T A-frags direct from global; zero elements j>48 in-register (NaN-safe)
    bf16x8 vf[2][2];
#pragma unroll
    for (int md = 0; md < 2; ++md) {
#pragma unroll
        for (int kk = 0; kk < 2; ++kk)
            vf[md][kk] = *(const bf16x8*)(vp + (md * 16 + lr) * 64 + kk * 32 + g * 8);
#pragma unroll
        for (int e = 0; e < 8; ++e)
            if (g * 8 + e > 16) vf[md][1][e] = (__bf16)0.0f;
    }

    const unsigned pbase = lds_addr(&Pt[h][0]);
    f32x4 accO[2][4] = {};  // [md][ni]: O^T row d = md*16+g*4+r, col i = ni*16+lr
#pragma unroll
    for (int kk = 0; kk < 2; ++kk) {
        long tt[4][2];
#pragma unroll
        for (int ni = 0; ni < 4; ++ni)
#pragma unroll
            for (int s = 0; s < 2; ++s) {
                unsigned a = pbase + ((((kk * 2 + s) * 4 + ni) * 4 + g) * 128) + lr * 2;
                asm volatile("ds_read_b64_tr_b16 %0, %1" : "=v"(tt[ni][s]) : "v"(a));
            }
        asm volatile("s_waitcnt lgkmcnt(0)" ::: "memory");
        __builtin_amdgcn_sched_barrier(0);
#pragma unroll
        for (int ni = 0; ni < 4; ++ni) {
            union { int4 i4; bf16x8 v; } u;
            u.i4 = make_int4((int)tt[ni][0], (int)(tt[ni][0] >> 32),
                             (int)tt[ni][1], (int)(tt[ni][1] >> 32));
#pragma unroll
            for (int md = 0; md < 2; ++md)
                accO[md][ni] = __builtin_amdgcn_mfma_f32_16x16x32_bf16(vf[md][kk], u.v, accO[md][ni], 0, 0, 0);
        }
    }
#pragma unroll
    for (int ni = 0; ni < 4; ++ni) {
        int i = ni * 16 + lr;
        if (i < 49) {
#pragma unroll
            for (int md = 0; md < 2; ++md) {
                ushort4 ov;
                ov.x = f2bf(accO[md][ni][0]);
                ov.y = f2bf(accO[md][ni][1]);
                ov.z = f2bf(accO[md][ni][2]);
                ov.w = f2bf(accO[md][ni][3]);
                *(ushort4*)(ob + ((long)(w * 49 + i)) * 128 + h * 32 + md * 16 + g * 4) = ov;
            }
        }
    }
}

extern "C" void kernel_launch(void* const* d_in, const int* in_sizes, int n_in,
                              void* d_out, int out_size, void* d_ws, size_t ws_size,
                              hipStream_t stream) {
    const float* x      = (const float*)d_in[0];
    const float* n1g    = (const float*)d_in[1];
    const float* n1b    = (const float*)d_in[2];
    const float* qkv_w  = (const float*)d_in[3];
    const float* qkv_b  = (const float*)d_in[4];
    const float* proj_w = (const float*)d_in[5];
    const float* proj_b = (const float*)d_in[6];
    const float* rpb    = (const float*)d_in[7];
    const float* n2g    = (const float*)d_in[8];
    const float* n2b    = (const float*)d_in[9];
    const float* fc1_w  = (const float*)d_in[10];
    const float* fc1_b  = (const float*)d_in[11];
    const float* fc2_w  = (const float*)d_in[12];
    const float* fc2_b  = (const float*)d_in[13];
    float* out = (float*)d_out;

    // Workspace (~324 MB):
    //  [0,SZ)             hnorm -> o -> h2[0:..]
    //  [SZ,3SZ+VT)        q | k | v^T   (contiguous, addressed by offset)
    //  [3SZ+VT, 4SZ+VT)   x2 bf16
    //  [4SZ+VT, 5SZ+VT)   h2norm
    //  [5SZ+VT, ..)       weights bf16 (384KB) + biasd (64KB)
    //  h2 = [0,4SZ) (hnorm/o, q, k, part of v^T regions, all dead by fc1)
    char* ws = (char*)d_ws;
    const size_t SZ = (size_t)M * C * 2;                    // 51,380,224
    const size_t VT = (size_t)NWIN * NH * 32 * 64 * 2;      // 67,108,864
    unsigned short* hnorm  = (unsigned short*)(ws);
    unsigned short* qkvbuf = (unsigned short*)(ws + SZ);
    unsigned short* o      = hnorm;
    unsigned short* x2b    = (unsigned short*)(ws + 3 * SZ + VT);
    unsigned short* h2n    = (unsigned short*)(ws + 4 * SZ + VT);
    unsigned short* h2     = (unsigned short*)(ws);
    unsigned short* wb     = (unsigned short*)(ws + 5 * SZ + VT);
    float* biasd           = (float*)(ws + 5 * SZ + VT + 393216);
    unsigned short* wqkv = wb, *wproj = wb + 49152, *wfc1 = wb + 65536, *wfc2 = wb + 131072;

    wconv_kernel<<<768, 256, 0, stream>>>(qkv_w, proj_w, fc1_w, fc2_w, rpb, biasd, wb);
    ln_kernel<false><<<M / 4, 256, 0, stream>>>(x, n1g, n1b, hnorm);
    gemm_mfma<0, 128, true ><<<dim3(M / 128, 3), 256, 0, stream>>>(hnorm, wqkv, qkv_b, nullptr, nullptr, nullptr, qkvbuf);
    attn_mfma<<<NWIN, 256, 0, stream>>>(qkvbuf, qkvbuf + (size_t)M * 128, qkvbuf + 2 * (size_t)M * 128, biasd, o);
    gemm_mfma<1, 128, false><<<dim3(M / 128, 1), 256, 0, stream>>>(o, wproj, proj_b, x, nullptr, nullptr, x2b);
    ln_kernel<true ><<<M / 4, 256, 0, stream>>>(x2b, n2g, n2b, h2n);
    gemm_mfma<2, 128, false><<<dim3(M / 128, 4), 256, 0, stream>>>(h2n, wfc1, fc1_b, nullptr, nullptr, nullptr, h2);
    gemm_mfma<3, 512, false><<<dim3(M / 128, 1), 256, 0, stream>>>(h2, wfc2, fc2_b, nullptr, x2b, out, nullptr);
}